// Round 15
// baseline (194.936 us; speedup 1.0000x reference)
//
#include <hip/hip_runtime.h>
#include <hip/hip_bf16.h>

// PoolAggregator: out[b,h] = mean_s relu( W @ features[idx[b,s]] + bias )
// B=10000, S=32, N=100000, D_IN=512, D_H=512.
//
// Pipeline (ws >= 205.7 MB):
//   0) cvt_bf16: feat f32 -> featb bf16 (padded to 100352 rows), W -> Wb bf16.
//   1) gemm8: H = relu(featb @ Wb^T + b) -> bf16. 256x256 tile, BK=64, 8 waves
//      (2Mx4N, per-wave 128x64), A/B double-buffered in 128KB LDS, 4-phase
//      schedule per K-tile: {ds_read A-frags | stage t+1 quarters (p0/p1) |
//      lgkmcnt+schedbar | setprio+16 MFMA | barrier}, vmcnt(0) only at tile
//      boundary (loads have 2-3 phases of cover). Granule-XOR swizzle (T2)
//      on all LDS tiles; B-frags register-cached per tile.
//   2) pool_mean4: out[b,:] = mean_s H[idx[b,s],:].
// Fallbacks: ws >= 102.4 MB -> f32-reg-staged gemm; else fused gather GEMM.

#define S_NB 32
#define D_IN 512
#define D_H  512
#define NNODE 100000
#define NPAD  100352                // 392 * 256
#define NBATCH 10000
#define NT8   784                   // (100352/256) * (512/256) = 392*2; 784 = 8*98

typedef __attribute__((ext_vector_type(8))) short  short8;
typedef __attribute__((ext_vector_type(4))) float  f32x4;
typedef __attribute__((ext_vector_type(4))) unsigned short us4;
typedef __attribute__((ext_vector_type(8))) unsigned short us8;

__device__ __forceinline__ unsigned short f2bf(float x) {
  union { float f; unsigned u; } v; v.f = x;
  unsigned r = v.u + 0x7FFFu + ((v.u >> 16) & 1u);
  return (unsigned short)(r >> 16);
}

__device__ __forceinline__ float bf2f(unsigned short x) {
  union { unsigned u; float f; } v; v.u = ((unsigned)x) << 16;
  return v.f;
}

// byte offset into a [rows][64]-bf16 LDS tile (row stride 128B) with XOR swizzle
__device__ __forceinline__ int swz(int row, int cb) {
  return row * 128 + (cb ^ ((row & 7) << 4));
}

// async global->LDS, 16B/lane
__device__ __forceinline__ void gld_lds16(const void* g, void* l) {
  __builtin_amdgcn_global_load_lds(
      (const __attribute__((address_space(1))) unsigned int*)g,
      (__attribute__((address_space(3))) unsigned int*)l, 16, 0, 0);
}

// ---------------- Phase 0: f32 -> bf16 streaming conversion ----------------
__global__ __launch_bounds__(256, 8)
void cvt_bf16(const float* __restrict__ src, unsigned short* __restrict__ dst, int n8) {
  int i = blockIdx.x * blockDim.x + threadIdx.x;
  const int stride = gridDim.x * blockDim.x;
  for (; i < n8; i += stride) {
    f32x4 a = *(const f32x4*)(src + (size_t)i * 8);
    f32x4 b = *(const f32x4*)(src + (size_t)i * 8 + 4);
    us8 o;
    o[0] = f2bf(a.x); o[1] = f2bf(a.y); o[2] = f2bf(a.z); o[3] = f2bf(a.w);
    o[4] = f2bf(b.x); o[5] = f2bf(b.y); o[6] = f2bf(b.z); o[7] = f2bf(b.w);
    *(us8*)(dst + (size_t)i * 8) = o;
  }
}

// ---------------- Phase 1: H = relu(featb @ Wb^T + b), 256x256 4-phase ----------------
// LDS byte layout: A[d] at d*32768 (256x64 bf16 = 32KB), B[d] at 65536 + d*32768.
__global__ __launch_bounds__(512, 1)
void gemm8(const unsigned short* __restrict__ featb,
           const unsigned short* __restrict__ Wb,
           const float* __restrict__ bias,
           unsigned short* __restrict__ Hb) {
  const int tid  = threadIdx.x;
  const int lane = tid & 63;
  const int w    = tid >> 6;            // wave 0..7
  const int wm   = w >> 2;              // 0..1 : M half (128 rows)
  const int wn   = w & 3;               // 0..3 : N quarter (64 cols)

  // XCD-chunked swizzle: 784 = 8 * 98; n-tile fastest (98 even -> pairs intact)
  const int bid  = blockIdx.x;
  const int tile = (bid & 7) * (NT8 / 8) + (bid >> 3);
  const int n0   = (tile & 1) * 256;
  const int m0   = (tile >> 1) * 256;

  __shared__ __align__(16) unsigned short lds8[65536];   // 128 KB
  char* ldsb = (char*)&lds8[0];

  // ---- staging geometry: quarter q = 128 rows x 64 cols = 16KB = 2 gload/thread.
  // wave w, instr j covers quarter-rows (w*2+j)*8 + (lane>>3); granule pos lane&7
  // holds source granule (lane&7)^(lane>>3)  (row&7 == lane>>3).
  const int srow = w * 16 + (lane >> 3);              // j=0 row-in-quarter
  const int g    = (lane & 7) ^ (lane >> 3);
  const unsigned short* sA = featb + (size_t)(m0 + srow) * D_IN + g * 8;
  const unsigned short* sB = Wb    + (size_t)(n0 + srow) * D_IN + g * 8;

  // stage quarter q of tile t into buffer d (A or B)
  auto stageA = [&](int d, int q, int t) {
    const unsigned short* s = sA + q * 65536 + t * 64;  // q*128 rows, t*BK cols
    unsigned short* o = &lds8[d * 16384 + q * 8192 + w * 1024];
    gld_lds16(s,        o);
    gld_lds16(s + 4096, o + 512);                       // j=1: +8 rows
  };
  auto stageB = [&](int d, int q, int t) {
    const unsigned short* s = sB + q * 65536 + t * 64;
    unsigned short* o = &lds8[32768 + d * 16384 + q * 8192 + w * 1024];
    gld_lds16(s,        o);
    gld_lds16(s + 4096, o + 512);
  };

  f32x4 acc[8][4];
#pragma unroll
  for (int i = 0; i < 8; ++i)
#pragma unroll
    for (int j = 0; j < 4; ++j)
      acc[i][j] = (f32x4){0.f, 0.f, 0.f, 0.f};

  // fragment-read geometry (R14-verified formulas; row stride 128B)
  const int frow = lane & 15;
  const int jg   = lane >> 4;
  const int kx0  = ((0 * 64) + jg * 16) ^ ((frow & 7) << 4);
  const int kx1  = ((1 * 64) + jg * 16) ^ ((frow & 7) << 4);
  const int arb  = (wm * 128 + frow) * 128;             // + mi*2048 + dA + kx
  const int brb  = 65536 + (wn * 64 + frow) * 128;      // + ni*2048 + dB + kx

  // ---- prologue: stage tile 0 (both operands), drain ----
  stageA(0, 0, 0); stageA(0, 1, 0);
  stageB(0, 0, 0); stageB(0, 1, 0);
  asm volatile("s_waitcnt vmcnt(0)" ::: "memory");
  __builtin_amdgcn_s_barrier();
  __builtin_amdgcn_sched_barrier(0);

  // ---- main loop: 8 K-tiles x 4 phases ----
#pragma unroll
  for (int t = 0; t < 8; ++t) {
    const int d  = (t & 1) * 32768;     // current buf byte offset
    short8 bfr[4][2];
#pragma unroll
    for (int p = 0; p < 4; ++p) {
      if (p == 0) {                     // B-frags cached for the whole tile
#pragma unroll
        for (int ni = 0; ni < 4; ++ni) {
          bfr[ni][0] = *(const short8*)(ldsb + brb + ni * 2048 + d + kx0);
          bfr[ni][1] = *(const short8*)(ldsb + brb + ni * 2048 + d + kx1);
        }
      }
      short8 af[2][2];
#pragma unroll
      for (int mii = 0; mii < 2; ++mii) {
        int mi = p * 2 + mii;
        af[mii][0] = *(const short8*)(ldsb + arb + mi * 2048 + d + kx0);
        af[mii][1] = *(const short8*)(ldsb + arb + mi * 2048 + d + kx1);
      }

      // stage tile t+1 quarters during p0/p1 (buf d^1 free since tile t-1's end)
      if (t < 7) {
        const int d1 = (t + 1) & 1;
        if (p == 0)      { stageA(d1, 0, t + 1); stageA(d1, 1, t + 1); }
        else if (p == 1) { stageB(d1, 0, t + 1); stageB(d1, 1, t + 1); }
      }

      asm volatile("s_waitcnt lgkmcnt(0)" ::: "memory");  // my frags valid
      __builtin_amdgcn_sched_barrier(0);                  // rule 18: pin MFMA after wait

      __builtin_amdgcn_s_setprio(1);
#pragma unroll
      for (int mii = 0; mii < 2; ++mii)
#pragma unroll
        for (int ni = 0; ni < 4; ++ni)
#pragma unroll
          for (int kk = 0; kk < 2; ++kk)
            acc[p * 2 + mii][ni] =
                __builtin_amdgcn_mfma_f32_16x16x32_bf16(af[mii][kk], bfr[ni][kk],
                                                        acc[p * 2 + mii][ni], 0, 0, 0);
      __builtin_amdgcn_s_setprio(0);

      if (p == 3 && t < 7)
        asm volatile("s_waitcnt vmcnt(0)" ::: "memory");  // t+1 loads landed (2-3 phases old)
      __builtin_amdgcn_s_barrier();
      __builtin_amdgcn_sched_barrier(0);
    }
  }

  // ---- Epilogue: bias+ReLU -> bf16 via XOR-swizzled 128KB overlay ----
  unsigned short* Cs = &lds8[0];        // 256 x 256 ushort = 128 KB (row stride 512B)
#pragma unroll
  for (int ni = 0; ni < 4; ++ni) {
    int col = wn * 64 + ni * 16 + frow;
    float bv = bias[n0 + col];
#pragma unroll
    for (int mi = 0; mi < 8; ++mi) {
#pragma unroll
      for (int r = 0; r < 4; ++r) {
        int row = wm * 128 + mi * 16 + jg * 4 + r;
        int byt = row * 512 + ((col * 2) ^ ((row & 7) << 4));
        *(unsigned short*)((char*)Cs + byt) = f2bf(fmaxf(acc[mi][ni][r] + bv, 0.f));
      }
    }
  }
  __syncthreads();

  const int scolg = tid & 31;           // 32 granules of 8 ushorts per 256-col row
#pragma unroll
  for (int it = 0; it < 16; ++it) {
    int row  = it * 16 + (tid >> 5);
    int grow = m0 + row;
    int byt  = row * 512 + ((scolg * 16) ^ ((row & 7) << 4));
    us8 v = *(const us8*)((const char*)Cs + byt);
    if (grow < NNODE)
      *(us8*)(Hb + (size_t)grow * D_H + n0 + scolg * 8) = v;
  }
}

// ---------------- Phase 2: out[b,:] = mean_s H[idx[b,s],:] ----------------
__global__ __launch_bounds__(256, 8)
void pool_mean4(const unsigned short* __restrict__ Hb,
                const int* __restrict__ nidx,
                float* __restrict__ out) {
  const int b4 = blockIdx.x;
  const int q  = threadIdx.x >> 6;
  const int t  = threadIdx.x & 63;
  const int b  = b4 * 4 + q;

  __shared__ int rows[4][S_NB];
  if (threadIdx.x < 4 * S_NB)
    rows[threadIdx.x >> 5][threadIdx.x & 31] = nidx[b4 * 4 * S_NB + threadIdx.x];
  __syncthreads();

  const int c = t * 8;
  float s0 = 0.f, s1 = 0.f, s2 = 0.f, s3 = 0.f;
  float s4 = 0.f, s5 = 0.f, s6 = 0.f, s7 = 0.f;
#pragma unroll
  for (int s = 0; s < S_NB; ++s) {
    us8 v = *(const us8*)(Hb + (size_t)rows[q][s] * D_H + c);
    s0 += bf2f(v[0]); s1 += bf2f(v[1]); s2 += bf2f(v[2]); s3 += bf2f(v[3]);
    s4 += bf2f(v[4]); s5 += bf2f(v[5]); s6 += bf2f(v[6]); s7 += bf2f(v[7]);
  }
  const float inv = 1.0f / (float)S_NB;
  f32x4 o1; o1.x = s0 * inv; o1.y = s1 * inv; o1.z = s2 * inv; o1.w = s3 * inv;
  f32x4 o2; o2.x = s4 * inv; o2.y = s5 * inv; o2.z = s6 * inv; o2.w = s7 * inv;
  *(f32x4*)(out + (size_t)b * D_H + c)     = o1;
  *(f32x4*)(out + (size_t)b * D_H + c + 4) = o2;
}

// ---------------- Fallback A: f32 reg-staged GEMM ----------------
__global__ __launch_bounds__(256, 4)
void gemm_h(const float* __restrict__ feat,
            const float* __restrict__ Wm,
            const float* __restrict__ bias,
            unsigned short* __restrict__ Hb) {
  const int tid  = threadIdx.x;
  const int lane = tid & 63;
  const int wid  = tid >> 6;
  const int wr   = wid >> 1;
  const int wc   = wid & 1;
  const int n0   = blockIdx.x * 128;
  const int m0   = blockIdx.y * 128;

  __shared__ __align__(16) unsigned short As[128 * 64];
  __shared__ __align__(16) unsigned short Bs[128 * 64];

  const int lr = tid >> 4;
  const int lc = tid & 15;

  const float* aptr[8];
  const float* wptr[8];
#pragma unroll
  for (int p = 0; p < 8; ++p) {
    int row = p * 16 + lr;
    int gr  = m0 + row; if (gr > NNODE - 1) gr = NNODE - 1;
    aptr[p] = feat + (size_t)gr * D_IN + lc * 4;
    wptr[p] = Wm + (size_t)(n0 + row) * D_IN + lc * 4;
  }

  f32x4 acc[4][4];
#pragma unroll
  for (int i = 0; i < 4; ++i)
#pragma unroll
    for (int j = 0; j < 4; ++j)
      acc[i][j] = (f32x4){0.f, 0.f, 0.f, 0.f};

  const int frow = lane & 15;
  const int kcb  = (lane >> 4) * 16;
  const int arow = wr * 64 + frow;
  const int brow = wc * 64 + frow;

  for (int k0 = 0; k0 < D_IN; k0 += 64) {
    __syncthreads();
#pragma unroll
    for (int p = 0; p < 8; ++p) {
      int row = p * 16 + lr;
      f32x4 av = *(const f32x4*)(aptr[p] + k0);
      f32x4 wv = *(const f32x4*)(wptr[p] + k0);
      us4 a4, w4;
      a4.x = f2bf(av.x); a4.y = f2bf(av.y); a4.z = f2bf(av.z); a4.w = f2bf(av.w);
      w4.x = f2bf(wv.x); w4.y = f2bf(wv.y); w4.z = f2bf(wv.z); w4.w = f2bf(wv.w);
      *(us4*)((char*)As + swz(row, lc * 8)) = a4;
      *(us4*)((char*)Bs + swz(row, lc * 8)) = w4;
    }
    __syncthreads();

#pragma unroll
    for (int kk = 0; kk < 2; ++kk) {
      short8 af[4], bfr[4];
#pragma unroll
      for (int mi = 0; mi < 4; ++mi)
        af[mi] = *(const short8*)((const char*)As + swz(arow + mi * 16, kk * 64 + kcb));
#pragma unroll
      for (int ni = 0; ni < 4; ++ni)
        bfr[ni] = *(const short8*)((const char*)Bs + swz(brow + ni * 16, kk * 64 + kcb));
#pragma unroll
      for (int mi = 0; mi < 4; ++mi)
#pragma unroll
        for (int ni = 0; ni < 4; ++ni)
          acc[mi][ni] = __builtin_amdgcn_mfma_f32_16x16x32_bf16(af[mi], bfr[ni], acc[mi][ni], 0, 0, 0);
    }
  }

  const int rq = lane >> 4;
#pragma unroll
  for (int ni = 0; ni < 4; ++ni) {
    int col = n0 + wc * 64 + ni * 16 + frow;
    float bv = bias[col];
#pragma unroll
    for (int mi = 0; mi < 4; ++mi) {
#pragma unroll
      for (int r = 0; r < 4; ++r) {
        int grow = m0 + wr * 64 + mi * 16 + rq * 4 + r;
        if (grow < NNODE)
          Hb[(size_t)grow * D_H + col] = f2bf(fmaxf(acc[mi][ni][r] + bv, 0.f));
      }
    }
  }
}

// ---------------- Fallback B: fused gathered GEMM (round-1) ----------------
__global__ __launch_bounds__(256, 4)
void pool_aggr_gemm(const int* __restrict__ nidx_g,
                    const float* __restrict__ feat,
                    const float* __restrict__ Wm,
                    const float* __restrict__ bias,
                    float* __restrict__ out) {
  const int tid  = threadIdx.x;
  const int lane = tid & 63;
  const int wid  = tid >> 6;
  const int wr   = wid >> 1;
  const int wc   = wid & 1;
  const int n0   = blockIdx.x * 128;
  const int mb   = blockIdx.y;

  __shared__ __align__(16) unsigned short As[128 * 64];
  __shared__ __align__(16) unsigned short Bs[128 * 64];
  __shared__ int nid[128];

  if (tid < 128) nid[tid] = nidx_g[mb * 128 + tid];
  __syncthreads();

  const int lr = tid >> 4;
  const int lc = tid & 15;

  const float* aptr[8];
  const float* wptr[8];
#pragma unroll
  for (int p = 0; p < 8; ++p) {
    int row = p * 16 + lr;
    aptr[p] = feat + (size_t)nid[row] * D_IN + lc * 4;
    wptr[p] = Wm + (size_t)(n0 + row) * D_IN + lc * 4;
  }

  f32x4 acc[4][4];
#pragma unroll
  for (int i = 0; i < 4; ++i)
#pragma unroll
    for (int j = 0; j < 4; ++j)
      acc[i][j] = (f32x4){0.f, 0.f, 0.f, 0.f};

  const int frow = lane & 15;
  const int kcb  = (lane >> 4) * 16;
  const int arow = wr * 64 + frow;
  const int brow = wc * 64 + frow;

  for (int k0 = 0; k0 < D_IN; k0 += 64) {
    __syncthreads();
#pragma unroll
    for (int p = 0; p < 8; ++p) {
      int row = p * 16 + lr;
      f32x4 av = *(const f32x4*)(aptr[p] + k0);
      f32x4 wv = *(const f32x4*)(wptr[p] + k0);
      us4 a4, w4;
      a4.x = f2bf(av.x); a4.y = f2bf(av.y); a4.z = f2bf(av.z); a4.w = f2bf(av.w);
      w4.x = f2bf(wv.x); w4.y = f2bf(wv.y); w4.z = f2bf(wv.z); w4.w = f2bf(wv.w);
      *(us4*)((char*)As + swz(row, lc * 8)) = a4;
      *(us4*)((char*)Bs + swz(row, lc * 8)) = w4;
    }
    __syncthreads();

#pragma unroll
    for (int kk = 0; kk < 2; ++kk) {
      short8 af[4], bfr[4];
#pragma unroll
      for (int mi = 0; mi < 4; ++mi)
        af[mi] = *(const short8*)((const char*)As + swz(arow + mi * 16, kk * 64 + kcb));
#pragma unroll
      for (int ni = 0; ni < 4; ++ni)
        bfr[ni] = *(const short8*)((const char*)Bs + swz(brow + ni * 16, kk * 64 + kcb));
#pragma unroll
      for (int mi = 0; mi < 4; ++mi)
#pragma unroll
        for (int ni = 0; ni < 4; ++ni)
          acc[mi][ni] = __builtin_amdgcn_mfma_f32_16x16x32_bf16(af[mi], bfr[ni], acc[mi][ni], 0, 0, 0);
    }
  }

  const int rq = lane >> 4;
#pragma unroll
  for (int ni = 0; ni < 4; ++ni) {
    int col = n0 + wc * 64 + ni * 16 + frow;
    float bv = bias[col];
#pragma unroll
    for (int bl = 0; bl < 2; ++bl) {
      float s = 0.f;
#pragma unroll
      for (int m2 = 0; m2 < 2; ++m2) {
        int mi = bl * 2 + m2;
#pragma unroll
        for (int r = 0; r < 4; ++r)
          s += fmaxf(acc[mi][ni][r] + bv, 0.f);
      }
      s += __shfl_xor(s, 16);
      s += __shfl_xor(s, 32);
      if (rq == 0) {
        int bb = mb * 4 + wr * 2 + bl;
        out[(size_t)bb * D_H + col] = s * (1.0f / (float)S_NB);
      }
    }
  }
}

extern "C" void kernel_launch(void* const* d_in, const int* in_sizes, int n_in,
                              void* d_out, int out_size, void* d_ws, size_t ws_size,
                              hipStream_t stream) {
  const int*   nidx = (const int*)d_in[0];    // [10000,32]
  const float* feat = (const float*)d_in[1];  // [100000,512]
  const float* Wm   = (const float*)d_in[2];  // [512,512]
  const float* bias = (const float*)d_in[3];  // [512]
  float* out = (float*)d_out;                 // [10000,512]

  const size_t featb_elems = (size_t)NPAD * D_IN;
  const size_t wb_elems    = (size_t)D_H * D_IN;
  const size_t h_elems     = (size_t)NNODE * D_H;
  const size_t need = (featb_elems + wb_elems + h_elems) * sizeof(unsigned short); // ~205.7 MB
  const size_t h_bytes = h_elems * sizeof(unsigned short);

  if (ws_size >= need) {
    unsigned short* featb = (unsigned short*)d_ws;
    unsigned short* Wb    = featb + featb_elems;
    unsigned short* Hb    = Wb + wb_elems;
    cvt_bf16<<<2048, 256, 0, stream>>>(feat, featb, NNODE * D_IN / 8);
    cvt_bf16<<<128, 256, 0, stream>>>(Wm, Wb, D_H * D_IN / 8);
    gemm8<<<NT8, 512, 0, stream>>>(featb, Wb, bias, Hb);
    pool_mean4<<<NBATCH / 4, 256, 0, stream>>>(Hb, nidx, out);
  } else if (ws_size >= h_bytes) {
    unsigned short* Hb = (unsigned short*)d_ws;
    dim3 g1(D_H / 128, (NNODE + 127) / 128);
    gemm_h<<<g1, 256, 0, stream>>>(feat, Wm, bias, Hb);
    pool_mean4<<<NBATCH / 4, 256, 0, stream>>>(Hb, nidx, out);
  } else {
    dim3 grid(D_H / 128, NBATCH / 4);
    pool_aggr_gemm<<<grid, 256, 0, stream>>>(nidx, feat, Wm, bias, out);
  }
}